// Round 8
// baseline (134.102 us; speedup 1.0000x reference)
//
#include <hip/hip_runtime.h>

// KA-conv: out[b,o,h,w] = sum_m P_om(v) / (1+|Q_om(v)|), v = zero-padded patch
// value, m = c*9+ki*3+kj, M=144. ~75.5M rational evals, pure fp32 VALU.
//
// R8: occupancy math is rigid — 524288 outputs == max resident threads, so
// full occupancy (8 waves/SIMD) with >=2 evals per coefficient fetch requires
// splitting the c-reduction across threads. Design:
//   512-thread block = 2 c-halves x 256 pixel-threads (8 rows x 64 cols tile,
//   2 rows/thread — the R5-proven data path). half0: c=0..7, half1: c=8..15.
//   Combine partials via 2KB LDS + one barrier (fixed-order add: determinism).
//   Grid 1024 -> 4 blocks/CU -> 32 waves/CU (hw max). R7's ds_bpermute
//   experiment reverted (failed correctness; direct loads are known-good).

constexpr int Bn = 4, Cin = 16, Hh = 64, Ww = 64, Oc = 32, Mtot = 144;

__global__ __launch_bounds__(512, 8)
void ka_conv_kernel(const float* __restrict__ x,
                    const float* __restrict__ nums,
                    const float* __restrict__ denoms,
                    float* __restrict__ out) {
  __shared__ float part[512];          // acc0 (256) + acc1 (256) of half 1

  const int tid  = threadIdx.x;
  const int pix  = tid & 255;          // pixel-slot within tile
  const int half = tid >> 8;           // 0: c=0..7, 1: c=8..15
  const int n    = blockIdx.x;
  const int ht   = n & 7;              // 8 row-tiles of 8 rows (low bits)
  const int o    = (n >> 3) & 31;      // output channel
  const int b    = n >> 8;             // batch

  const int w  = pix & 63;             // lane == output column
  const int rg = pix >> 6;             // rowgroup 0..3
  const int h0 = ht * 8 + rg * 2;      // this thread's 2 output rows

  // clamped neighbor rows/cols + validity masks (loop-invariant)
  const int  wm   = max(w - 1, 0), wp = min(w + 1, Ww - 1);
  const bool wl   = w > 0, wr = (w + 1) < Ww;
  const int  h_1  = max(h0 - 1, 0);        // top halo row (clamped)
  const int  h2c  = min(h0 + 2, Hh - 1);   // bottom halo row (clamped)
  const bool htv  = h0 > 0, hbv = (h0 + 2) < Hh;
  const bool tl = htv && wl, tr_ = htv && wr;
  const bool bl = hbv && wl, br = hbv && wr;

  float acc0 = 0.f, acc1 = 0.f;
  const float* __restrict__ xb   = x + (size_t)b * Cin * Hh * Ww;
  const float* __restrict__ anum = nums   + (size_t)o * Mtot * 6;  // uniform
  const float* __restrict__ bden = denoms + (size_t)o * Mtot * 4;  // uniform

  // one tap: coeff slot t (0..8) of channel c; vt -> acc0 (row h0),
  // vb -> acc1 (row h0+1). pa/pb wave-uniform -> s_load w/ imm offsets.
#define TAP(t, vt, vb) do {                                                    \
    const float a0 = pa[(t)*6 + 0], a1 = pa[(t)*6 + 1], a2 = pa[(t)*6 + 2];    \
    const float a3 = pa[(t)*6 + 3], a4 = pa[(t)*6 + 4], a5 = pa[(t)*6 + 5];    \
    const float c1 = pb[(t)*4 + 0], c2 = pb[(t)*4 + 1];                        \
    const float c3 = pb[(t)*4 + 2], c4 = pb[(t)*4 + 3];                        \
    {                                                                          \
      const float v  = (vt);                                                   \
      float num = fmaf(fmaf(fmaf(fmaf(fmaf(a5,v,a4),v,a3),v,a2),v,a1),v,a0);   \
      float dp  = fmaf(fmaf(fmaf(c4,v,c3),v,c2),v,c1) * v;                     \
      float r   = __builtin_amdgcn_rcpf(1.0f + fabsf(dp));                     \
      acc0 = fmaf(num, r, acc0);                                               \
    }                                                                          \
    {                                                                          \
      const float v  = (vb);                                                   \
      float num = fmaf(fmaf(fmaf(fmaf(fmaf(a5,v,a4),v,a3),v,a2),v,a1),v,a0);   \
      float dp  = fmaf(fmaf(fmaf(c4,v,c3),v,c2),v,c1) * v;                     \
      float r   = __builtin_amdgcn_rcpf(1.0f + fabsf(dp));                     \
      acc1 = fmaf(num, r, acc1);                                               \
    }                                                                          \
  } while (0)

  const int cBeg = half * (Cin / 2);        // 0 or 8
  #pragma unroll 2
  for (int ci = 0; ci < Cin / 2; ++ci) {
    const int c = cBeg + ci;
    const float* __restrict__ xc = xb + (size_t)c * (Hh * Ww);
    const float* __restrict__ r0 = xc + h_1 * Ww;       // h0-1 (clamped)
    const float* __restrict__ r1 = xc + h0 * Ww;        // h0
    const float* __restrict__ r2 = xc + (h0 + 1) * Ww;  // h0+1
    const float* __restrict__ r3 = xc + h2c * Ww;       // h0+2 (clamped)

    // 12 unconditional coalesced loads, then mask halo lanes to zero
    float v00 = r0[wm], v01 = r0[w], v02 = r0[wp];
    float v10 = r1[wm], v11 = r1[w], v12 = r1[wp];
    float v20 = r2[wm], v21 = r2[w], v22 = r2[wp];
    float v30 = r3[wm], v31 = r3[w], v32 = r3[wp];
    v00 = tl  ? v00 : 0.f;  v01 = htv ? v01 : 0.f;  v02 = tr_ ? v02 : 0.f;
    v10 = wl  ? v10 : 0.f;                          v12 = wr  ? v12 : 0.f;
    v20 = wl  ? v20 : 0.f;                          v22 = wr  ? v22 : 0.f;
    v30 = bl  ? v30 : 0.f;  v31 = hbv ? v31 : 0.f;  v32 = br  ? v32 : 0.f;

    const float* __restrict__ pa = anum + c * 54;   // 9 taps * 6 coeffs
    const float* __restrict__ pb = bden + c * 36;   // 9 taps * 4 coeffs
    // ki=0: rows (h0-1,h0); ki=1: (h0,h0+1); ki=2: (h0+1,h0+2)
    TAP(0, v00, v10);  TAP(1, v01, v11);  TAP(2, v02, v12);
    TAP(3, v10, v20);  TAP(4, v11, v21);  TAP(5, v12, v22);
    TAP(6, v20, v30);  TAP(7, v21, v31);  TAP(8, v22, v32);
  }
#undef TAP

  // combine the two c-halves: half1 -> LDS, half0 adds and stores.
  if (half == 1) {
    part[pix]       = acc0;
    part[pix + 256] = acc1;
  }
  __syncthreads();
  if (half == 0) {
    const float s0 = acc0 + part[pix];
    const float s1 = acc1 + part[pix + 256];
    float* op = out + ((size_t)(b * Oc + o) * Hh + h0) * Ww + w;
    op[0]  = s0;
    op[Ww] = s1;
  }
}

extern "C" void kernel_launch(void* const* d_in, const int* in_sizes, int n_in,
                              void* d_out, int out_size, void* d_ws, size_t ws_size,
                              hipStream_t stream) {
  const float* x      = (const float*)d_in[0];
  const float* nums   = (const float*)d_in[1];
  const float* denoms = (const float*)d_in[2];
  float* out          = (float*)d_out;
  // blockIdx = (b*32 + o)*8 + ht
  dim3 grid(Bn * Oc * 8);
  ka_conv_kernel<<<grid, 512, 0, stream>>>(x, nums, denoms, out);
}

// Round 9
// 41.411 us; speedup vs baseline: 3.2383x; 3.2383x over previous
//
#include <hip/hip_runtime.h>

// KA-conv: out[b,o,h,w] = sum_m P_om(v) / (1+|Q_om(v)|), v = zero-padded patch
// value, m = c*9+ki*3+kj, M=144. ~75.5M rational evals, pure fp32 VALU.
//
// R9: evidence from R6/R8: __launch_bounds__ min-waves=8 makes the compiler
// clamp to 32 VGPR and SPILL (R8: 345MB scratch writes; R6: 1.6x instr
// inflation). min-waves=4 builds are clean 64-VGPR (R4/R5). R5's occupancy
// was grid-capped (1024 blocks x 4 waves = 50% of device), not VGPR-capped.
// So: R6's full-device geometry (1 row/thread, grid 2048x256 = 32 waves/CU
// potential) + launch_bounds(256,4) so the compiler allocates ~48-64 VGPR
// spill-free (still physically allows 8 waves/SIMD). Direct 9-load patch
// (R7 bpermute reverted), o->readfirstlane => s_load coeffs on SMEM pipe,
// ht-in-low-bits so co-resident blocks share one coefficient set.

constexpr int Bn = 4, Cin = 16, Hh = 64, Ww = 64, Oc = 32, Mtot = 144;

__global__ __launch_bounds__(256, 4)
void ka_conv_kernel(const float* __restrict__ x,
                    const float* __restrict__ nums,
                    const float* __restrict__ denoms,
                    float* __restrict__ out) {
  const int tid = threadIdx.x;
  const int n   = blockIdx.x;
  const int ht  = n & 15;                 // 16 height tiles of 4 rows (low)
  const int o   = __builtin_amdgcn_readfirstlane((n >> 4) & 31);  // uniform
  const int b   = n >> 9;                 // batch

  const int w  = tid & 63;                // lane == output column
  const int rg = tid >> 6;                // row-in-tile 0..3
  const int h  = ht * 4 + rg;             // this thread's single output row

  // clamped neighbor rows/cols + validity masks (loop-invariant)
  const int  wm  = max(w - 1, 0), wp = min(w + 1, Ww - 1);
  const bool wlv = w > 0, wrv = (w + 1) < Ww;
  const int  hm  = max(h - 1, 0), hp = min(h + 1, Hh - 1);
  const bool htv = h > 0, hbv = (h + 1) < Hh;
  const bool m00 = htv && wlv, m01 = htv, m02 = htv && wrv;
  const bool m10 = wlv,                    m12 = wrv;
  const bool m20 = hbv && wlv, m21 = hbv, m22 = hbv && wrv;

  float acc = 0.f;
  const float* __restrict__ xb   = x + (size_t)b * Cin * Hh * Ww;
  const float* __restrict__ anum = nums   + (size_t)o * Mtot * 6;   // uniform
  const float* __restrict__ bden = denoms + (size_t)o * Mtot * 4;   // uniform

  // one tap: coeff slot t (0..8) of channel c, patch value v -> acc.
  // pa/pb wave-uniform -> s_load with immediate offsets.
#define TAP(t, v_) do {                                                        \
    const float a0 = pa[(t)*6 + 0], a1 = pa[(t)*6 + 1], a2 = pa[(t)*6 + 2];    \
    const float a3 = pa[(t)*6 + 3], a4 = pa[(t)*6 + 4], a5 = pa[(t)*6 + 5];    \
    const float c1 = pb[(t)*4 + 0], c2 = pb[(t)*4 + 1];                        \
    const float c3 = pb[(t)*4 + 2], c4 = pb[(t)*4 + 3];                        \
    const float v  = (v_);                                                     \
    float num = fmaf(fmaf(fmaf(fmaf(fmaf(a5,v,a4),v,a3),v,a2),v,a1),v,a0);     \
    float dp  = fmaf(fmaf(fmaf(c4,v,c3),v,c2),v,c1) * v;                       \
    float r   = __builtin_amdgcn_rcpf(1.0f + fabsf(dp));                       \
    acc = fmaf(num, r, acc);                                                   \
  } while (0)

  #pragma unroll 2
  for (int c = 0; c < Cin; ++c) {
    const float* __restrict__ xc = xb + (size_t)c * (Hh * Ww);
    const float* __restrict__ r0 = xc + hm * Ww;        // h-1 (clamped)
    const float* __restrict__ r1 = xc + h * Ww;         // h
    const float* __restrict__ r2 = xc + hp * Ww;        // h+1 (clamped)

    // 9 unconditional coalesced loads, then mask halo lanes to zero
    float v00 = r0[wm], v01 = r0[w], v02 = r0[wp];
    float v10 = r1[wm], v11 = r1[w], v12 = r1[wp];
    float v20 = r2[wm], v21 = r2[w], v22 = r2[wp];
    v00 = m00 ? v00 : 0.f;  v01 = m01 ? v01 : 0.f;  v02 = m02 ? v02 : 0.f;
    v10 = m10 ? v10 : 0.f;                          v12 = m12 ? v12 : 0.f;
    v20 = m20 ? v20 : 0.f;  v21 = m21 ? v21 : 0.f;  v22 = m22 ? v22 : 0.f;

    const float* __restrict__ pa = anum + c * 54;   // 9 taps * 6 coeffs
    const float* __restrict__ pb = bden + c * 36;   // 9 taps * 4 coeffs
    TAP(0, v00);  TAP(1, v01);  TAP(2, v02);
    TAP(3, v10);  TAP(4, v11);  TAP(5, v12);
    TAP(6, v20);  TAP(7, v21);  TAP(8, v22);
  }
#undef TAP

  out[((size_t)(b * Oc + o) * Hh + h) * Ww + w] = acc;
}

extern "C" void kernel_launch(void* const* d_in, const int* in_sizes, int n_in,
                              void* d_out, int out_size, void* d_ws, size_t ws_size,
                              hipStream_t stream) {
  const float* x      = (const float*)d_in[0];
  const float* nums   = (const float*)d_in[1];
  const float* denoms = (const float*)d_in[2];
  float* out          = (float*)d_out;
  // blockIdx = b*512 + o*16 + ht  (ht in low bits)
  dim3 grid(Bn * Oc * 16);
  ka_conv_kernel<<<grid, 256, 0, stream>>>(x, nums, denoms, out);
}

// Round 10
// 32.316 us; speedup vs baseline: 4.1497x; 1.2814x over previous
//
#include <hip/hip_runtime.h>

// KA-conv: out[b,o,h,w] = sum_m P_om(v) / (1+|Q_om(v)|), v = zero-padded patch
// value, m = c*9+ki*3+kj, M=144. ~75.5M rational evals, pure fp32 VALU.
//
// R10: R5/R9 triangulation: busy-time == per-config instruction model; idle
// ~15us regardless of occupancy; R=2 rows/thread is the best amortization
// point (33.8us). New lever: MI355X's 157.3TF fp32 = 2 FMA/lane/cyc-pair via
// v_pk_fma_f32 — scalar v_fma caps at half rate. The 2-row pair is a natural
// <2 x float>: both rows' Horner chains as vector fma (__builtin_elementwise_
// fma -> v_pk_fma_f32 on gfx950). ~2x fewer FMA issue slots; rcp stays
// scalar. Arithmetic identical to R5 -> worst case neutral.
// Structure otherwise == R5 (best): 256-thr blocks, grid 1024, 2 rows/thread,
// s_load coeffs via readfirstlane-uniform o, ht-in-low-bits, unroll 2.

constexpr int Bn = 4, Cin = 16, Hh = 64, Ww = 64, Oc = 32, Mtot = 144;

typedef float v2f __attribute__((ext_vector_type(2)));

__global__ __launch_bounds__(256, 4)
void ka_conv_kernel(const float* __restrict__ x,
                    const float* __restrict__ nums,
                    const float* __restrict__ denoms,
                    float* __restrict__ out) {
  const int tid = threadIdx.x;
  const int n   = blockIdx.x;
  const int ht  = n & 7;                  // 8 height tiles of 8 rows (low bits)
  const int o   = __builtin_amdgcn_readfirstlane((n >> 3) & 31);  // uniform
  const int b   = n >> 8;                 // batch

  const int w  = tid & 63;                // lane == output column
  const int rg = tid >> 6;                // rowgroup 0..3
  const int h0 = ht * 8 + rg * 2;         // this thread's 2 output rows

  // clamped neighbor rows/cols + validity masks (loop-invariant)
  const int  wm   = max(w - 1, 0), wp = min(w + 1, Ww - 1);
  const bool wl   = w > 0, wr = (w + 1) < Ww;
  const int  h_1  = max(h0 - 1, 0);        // top halo row (clamped)
  const int  h2c  = min(h0 + 2, Hh - 1);   // bottom halo row (clamped)
  const bool htv  = h0 > 0, hbv = (h0 + 2) < Hh;
  const bool tl = htv && wl, tr_ = htv && wr;
  const bool bl = hbv && wl, br = hbv && wr;

  v2f acc = {0.f, 0.f};                    // (row h0, row h0+1)
  const float* __restrict__ xb   = x + (size_t)b * Cin * Hh * Ww;
  const float* __restrict__ anum = nums   + (size_t)o * Mtot * 6;  // uniform
  const float* __restrict__ bden = denoms + (size_t)o * Mtot * 4;  // uniform

  // one tap: coeff slot t (0..8) of channel c; (vt,vb) -> acc as a packed
  // pair. Coefficients are wave-uniform s_loads; Horner chains run as
  // <2 x float> fma -> v_pk_fma_f32.
#define TAP(t, vt, vb) do {                                                    \
    const float a0 = pa[(t)*6 + 0], a1 = pa[(t)*6 + 1], a2 = pa[(t)*6 + 2];    \
    const float a3 = pa[(t)*6 + 3], a4 = pa[(t)*6 + 4], a5 = pa[(t)*6 + 5];    \
    const float c1 = pb[(t)*4 + 0], c2 = pb[(t)*4 + 1];                        \
    const float c3 = pb[(t)*4 + 2], c4 = pb[(t)*4 + 3];                        \
    const v2f v = {(vt), (vb)};                                                \
    v2f num = __builtin_elementwise_fma((v2f){a5, a5}, v, (v2f){a4, a4});      \
    num = __builtin_elementwise_fma(num, v, (v2f){a3, a3});                    \
    num = __builtin_elementwise_fma(num, v, (v2f){a2, a2});                    \
    num = __builtin_elementwise_fma(num, v, (v2f){a1, a1});                    \
    num = __builtin_elementwise_fma(num, v, (v2f){a0, a0});                    \
    v2f dp = __builtin_elementwise_fma((v2f){c4, c4}, v, (v2f){c3, c3});       \
    dp = __builtin_elementwise_fma(dp, v, (v2f){c2, c2});                      \
    dp = __builtin_elementwise_fma(dp, v, (v2f){c1, c1});                      \
    dp = dp * v;                                                               \
    const v2f den = (v2f){1.f, 1.f} + __builtin_elementwise_abs(dp);           \
    const v2f r = {__builtin_amdgcn_rcpf(den.x), __builtin_amdgcn_rcpf(den.y)};\
    acc = __builtin_elementwise_fma(num, r, acc);                              \
  } while (0)

  #pragma unroll 2
  for (int c = 0; c < Cin; ++c) {
    const float* __restrict__ xc = xb + (size_t)c * (Hh * Ww);
    const float* __restrict__ r0 = xc + h_1 * Ww;       // h0-1 (clamped)
    const float* __restrict__ r1 = xc + h0 * Ww;        // h0
    const float* __restrict__ r2 = xc + (h0 + 1) * Ww;  // h0+1
    const float* __restrict__ r3 = xc + h2c * Ww;       // h0+2 (clamped)

    // 12 unconditional coalesced loads, then mask halo lanes to zero
    float v00 = r0[wm], v01 = r0[w], v02 = r0[wp];
    float v10 = r1[wm], v11 = r1[w], v12 = r1[wp];
    float v20 = r2[wm], v21 = r2[w], v22 = r2[wp];
    float v30 = r3[wm], v31 = r3[w], v32 = r3[wp];
    v00 = tl  ? v00 : 0.f;  v01 = htv ? v01 : 0.f;  v02 = tr_ ? v02 : 0.f;
    v10 = wl  ? v10 : 0.f;                          v12 = wr  ? v12 : 0.f;
    v20 = wl  ? v20 : 0.f;                          v22 = wr  ? v22 : 0.f;
    v30 = bl  ? v30 : 0.f;  v31 = hbv ? v31 : 0.f;  v32 = br  ? v32 : 0.f;

    const float* __restrict__ pa = anum + c * 54;   // 9 taps * 6 coeffs
    const float* __restrict__ pb = bden + c * 36;   // 9 taps * 4 coeffs
    // ki=0: rows (h0-1,h0); ki=1: (h0,h0+1); ki=2: (h0+1,h0+2)
    TAP(0, v00, v10);  TAP(1, v01, v11);  TAP(2, v02, v12);
    TAP(3, v10, v20);  TAP(4, v11, v21);  TAP(5, v12, v22);
    TAP(6, v20, v30);  TAP(7, v21, v31);  TAP(8, v22, v32);
  }
#undef TAP

  float* op = out + ((size_t)(b * Oc + o) * Hh + h0) * Ww + w;
  op[0]  = acc.x;
  op[Ww] = acc.y;
}

extern "C" void kernel_launch(void* const* d_in, const int* in_sizes, int n_in,
                              void* d_out, int out_size, void* d_ws, size_t ws_size,
                              hipStream_t stream) {
  const float* x      = (const float*)d_in[0];
  const float* nums   = (const float*)d_in[1];
  const float* denoms = (const float*)d_in[2];
  float* out          = (float*)d_out;
  // blockIdx = (b*32 + o)*8 + ht   (ht in low bits)
  dim3 grid(Bn * Oc * 8);
  ka_conv_kernel<<<grid, 256, 0, stream>>>(x, nums, denoms, out);
}